// Round 1
// 475.439 us; speedup vs baseline: 80.4872x; 80.4872x over previous
//
#include <hip/hip_runtime.h>
#include <hip/hip_bf16.h>

// R6: full bf16-MFMA rewrite.
//  - proj_mfma: m97-structure 128x128 tile GEMM (16x16x32 bf16 MFMA),
//    fp32->bf16 conversion fused into LDS staging (dtype-detect per R5).
//  - attn_mfma: flash attention, 4 waves x 16 q-rows, 64-key LDS tiles,
//    XOR-swizzled 128B LDS rows (G4), online softmax via 16-lane shfl.
//  - scratch: Q/K/V/X bf16 in d_ws (33.5MB); R5 slow path kept as fallback
//    for small-ws worlds.
// Deliberately NO global_load_lds / inline-asm scheduling this round:
// structure + correctness first, async staging next round.

#define B_ 2
#define S_ 2048
#define D_ 1024
#define H_ 16
#define HD_ 64

typedef unsigned short u16;
typedef unsigned int u32;
typedef u16 __attribute__((may_alias)) u16_ma;
typedef float __attribute__((may_alias)) f32_ma;
typedef u32 v4u __attribute__((ext_vector_type(4)));
typedef v4u __attribute__((may_alias)) v4u_ma;
typedef short bf16x8 __attribute__((ext_vector_type(8)));
typedef bf16x8 __attribute__((may_alias)) bf16x8_ma;
typedef float f32x4 __attribute__((ext_vector_type(4)));

__device__ __forceinline__ float bf2f(u16 u) {
  u32 x = ((u32)u) << 16;
  return __builtin_bit_cast(float, x);
}
__device__ __forceinline__ u16 f2bf(float f) {
  __hip_bfloat16 h = __float2bfloat16(f);
  return __builtin_bit_cast(u16, h);
}
// pack two fp32 (given as bit patterns) into a bf16x2 dword
__device__ __forceinline__ u32 pk2(u32 alo, u32 ahi) {
  return (u32)f2bf(__builtin_bit_cast(float, alo)) |
         ((u32)f2bf(__builtin_bit_cast(float, ahi)) << 16);
}

// Input dtype detect (R5, harness-verified): scan first 2048 u16 of a weight
// buffer for an exponent-field >= 0xF0. bf16 weights ~N(0,4e-4) never hit;
// fp32 mantissa bytes hit w.p. ~1/16 per u32 -> certain across 64 lanes.
__device__ __forceinline__ bool detect_f32(const u16* Wg) {
  const int lane = threadIdx.x & 63;
  bool hit = false;
#pragma unroll
  for (int i = 0; i < 4; ++i) {
    v4u u = *(const v4u_ma*)(Wg + lane * 32 + i * 8);
#pragma unroll
    for (int j = 0; j < 4; ++j) {
      u32 w = u[j];
      hit |= (((w >> 7) & 0xFFu) >= 0xF0u) || (((w >> 23) & 0xFFu) >= 0xF0u);
    }
  }
  return __any(hit);
}

// ---------------------------------------------------------------------------
// Stage a [128 rows x 32 k] bf16 tile into LDS from a row-major source with
// row stride 1024 elements. If f32, convert during staging. Linear LDS layout
// (m97-style; the 8-way read aliasing is the known-acceptable m97 cost).
// ---------------------------------------------------------------------------
__device__ __forceinline__ void stage_tile(u16* lds, const void* src, bool f32,
                                           int rbase, int k0, int tid) {
  const int rr = tid >> 2;         // 0..63
  const int e0 = (tid & 3) * 8;    // elem col in 32-wide tile
#pragma unroll
  for (int p = 0; p < 2; ++p) {
    const int row = p * 64 + rr;
    const size_t off = (size_t)(rbase + row) * 1024 + k0 + e0;
    v4u val;
    if (f32) {
      const v4u_ma* fp = (const v4u_ma*)((const float*)src + off);
      v4u f0 = fp[0], f1 = fp[1];
      val[0] = pk2(f0[0], f0[1]);
      val[1] = pk2(f0[2], f0[3]);
      val[2] = pk2(f1[0], f1[1]);
      val[3] = pk2(f1[2], f1[3]);
    } else {
      val = *(const v4u_ma*)((const u16*)src + off);
    }
    *(v4u_ma*)(lds + row * 32 + e0) = val;
  }
}

// ---------------------------------------------------------------------------
// C[4096,1024] = A[4096,1024] @ W[1024,1024]^T  (torch Linear)
// 128x128 block, 4 waves (2x2), each wave 64x64 = 4x4 MFMA fragments.
// A_BF16: A is bf16 scratch (else dtype per detect). OUT_DET: C dtype per
// detect (final proj) else bf16 scratch.
// ---------------------------------------------------------------------------
template <bool A_BF16, bool OUT_DET>
__global__ __launch_bounds__(256) void proj_mfma(
    const void* __restrict__ Ag, const void* __restrict__ Wg,
    void* __restrict__ Cg, const u16* __restrict__ Wdet) {
  const bool det = detect_f32(Wdet);
  const bool a_f32 = A_BF16 ? false : det;

  __shared__ u16 Al[128 * 32];
  __shared__ u16 Wl[128 * 32];

  const int tid = threadIdx.x;
  const int lane = tid & 63;
  const int wid = tid >> 6;
  const int lg = lane >> 4, li = lane & 15;
  const int wr = wid >> 1, wc = wid & 1;
  const int m0 = blockIdx.x * 128, n0 = blockIdx.y * 128;

  f32x4 acc[4][4];
#pragma unroll
  for (int m = 0; m < 4; ++m)
#pragma unroll
    for (int n = 0; n < 4; ++n) acc[m][n] = (f32x4){0.f, 0.f, 0.f, 0.f};

  for (int kt = 0; kt < 32; ++kt) {
    const int k0 = kt * 32;
    __syncthreads();
    stage_tile(Al, Ag, a_f32, m0, k0, tid);
    stage_tile(Wl, Wg, det, n0, k0, tid);
    __syncthreads();

    bf16x8 af[4], bw[4];
#pragma unroll
    for (int m = 0; m < 4; ++m)
      af[m] = *(const bf16x8_ma*)(Al + (wr * 64 + m * 16 + li) * 32 + lg * 8);
#pragma unroll
    for (int n = 0; n < 4; ++n)
      bw[n] = *(const bf16x8_ma*)(Wl + (wc * 64 + n * 16 + li) * 32 + lg * 8);
#pragma unroll
    for (int m = 0; m < 4; ++m)
#pragma unroll
      for (int n = 0; n < 4; ++n)
        acc[m][n] =
            __builtin_amdgcn_mfma_f32_16x16x32_bf16(af[m], bw[n], acc[m][n], 0, 0, 0);
  }

  const bool out_f32 = OUT_DET ? det : false;
#pragma unroll
  for (int m = 0; m < 4; ++m)
#pragma unroll
    for (int n = 0; n < 4; ++n)
#pragma unroll
      for (int r = 0; r < 4; ++r) {
        const int row = m0 + wr * 64 + m * 16 + lg * 4 + r;
        const int col = n0 + wc * 64 + n * 16 + li;
        const size_t idx = (size_t)row * 1024 + col;
        const float v = acc[m][n][r];
        if (out_f32)
          ((f32_ma*)Cg)[idx] = v;
        else
          ((u16_ma*)Cg)[idx] = f2bf(v);
      }
}

// ---------------------------------------------------------------------------
// Flash attention, all-bf16 scratch. Block = 4 waves, 64 q-rows (16/wave).
// Per 64-key tile: stage K [64k][64d] + V^T [64d][64k] in LDS (XOR-swizzled
// 128B rows), QK^T via MFMA (Q in regs), online softmax (rows live on
// 16-lane groups), P->LDS->A-fragment, PV via MFMA into fp32 accumulators.
// ---------------------------------------------------------------------------
__global__ __launch_bounds__(256) void attn_mfma(
    const u16* __restrict__ Qg, const u16* __restrict__ Kg,
    const u16* __restrict__ Vg, u16* __restrict__ Og) {
  __shared__ u16 Kl[64 * 64];
  __shared__ u16 VTl[64 * 64];
  __shared__ u16 Pl[4][16 * 64];

  const int tid = threadIdx.x;
  const int wid = tid >> 6, lane = tid & 63;
  const int lg = lane >> 4, li = lane & 15;

  const int qb = blockIdx.x & 31;
  const int h = (blockIdx.x >> 5) & 15;
  const int b = blockIdx.x >> 9;
  const size_t bbase = (size_t)b * S_ * D_;
  const int hoff = h * HD_;

  // Q A-fragments: lane holds Q[q0+li][c*32 + lg*8 + j]
  bf16x8 aq0, aq1;
  {
    const u16* qp =
        Qg + bbase + (size_t)(qb * 64 + wid * 16 + li) * D_ + hoff + lg * 8;
    aq0 = *(const bf16x8_ma*)(qp);
    aq1 = *(const bf16x8_ma*)(qp + 32);
  }

  f32x4 o[4];
#pragma unroll
  for (int t = 0; t < 4; ++t) o[t] = (f32x4){0.f, 0.f, 0.f, 0.f};
  float mrun[4] = {-1e30f, -1e30f, -1e30f, -1e30f};
  float lrun[4] = {0.f, 0.f, 0.f, 0.f};

  const int krr = tid >> 3;       // K-stage: row (+32/pass), 8 lanes/row
  const int kc8 = (tid & 7) * 8;  // K-stage: elem col
  const int vkr = lane;           // V-stage: key row = lane (bank-friendly)
  const int vd0 = wid * 8;        // V-stage: d-group base (+32/pass)

  for (int kt = 0; kt < S_ / 64; ++kt) {
    const int key0 = kt * 64;
    __syncthreads();
    // stage K [64 keys][64 d]
#pragma unroll
    for (int p = 0; p < 2; ++p) {
      const int row = p * 32 + krr;
      v4u val =
          *(const v4u_ma*)(Kg + bbase + (size_t)(key0 + row) * D_ + hoff + kc8);
      *(v4u_ma*)((char*)Kl + row * 128 + ((kc8 * 2) ^ ((row & 7) << 4))) = val;
    }
    // stage V^T [64 d][64 keys] (transpose in flight, scalar swizzled writes)
#pragma unroll
    for (int p = 0; p < 2; ++p) {
      const int dd = vd0 + p * 32;
      v4u val =
          *(const v4u_ma*)(Vg + bbase + (size_t)(key0 + vkr) * D_ + hoff + dd);
      union {
        v4u v;
        u16 e[8];
      } uu;
      uu.v = val;
#pragma unroll
      for (int j = 0; j < 8; ++j) {
        const int d = dd + j;
        *(u16*)((char*)VTl + d * 128 + ((vkr * 2) ^ ((d & 7) << 4))) = uu.e[j];
      }
    }
    __syncthreads();

    // QK^T -> S[16 q][64 k] per wave (C-layout: row=lg*4+r, col=li)
    f32x4 s[4];
#pragma unroll
    for (int kk = 0; kk < 4; ++kk) {
      const int row = kk * 16 + li;
      const char* kb = (const char*)Kl + row * 128;
      const int sw = (row & 7) << 4;
      bf16x8 b0 = *(const bf16x8_ma*)(kb + ((lg * 16) ^ sw));
      bf16x8 b1 = *(const bf16x8_ma*)(kb + ((64 + lg * 16) ^ sw));
      f32x4 z = (f32x4){0.f, 0.f, 0.f, 0.f};
      z = __builtin_amdgcn_mfma_f32_16x16x32_bf16(aq0, b0, z, 0, 0, 0);
      z = __builtin_amdgcn_mfma_f32_16x16x32_bf16(aq1, b1, z, 0, 0, 0);
      s[kk] = z * 0.125f;  // 1/sqrt(64)
    }

    // online softmax; row r lives on the 16 lanes of group lg
    float al[4];
#pragma unroll
    for (int r = 0; r < 4; ++r) {
      float t0 = fmaxf(fmaxf(s[0][r], s[1][r]), fmaxf(s[2][r], s[3][r]));
#pragma unroll
      for (int off = 1; off < 16; off <<= 1) t0 = fmaxf(t0, __shfl_xor(t0, off));
      const float mn = fmaxf(mrun[r], t0);
      al[r] = __expf(mrun[r] - mn);
      mrun[r] = mn;
    }
#pragma unroll
    for (int r = 0; r < 4; ++r) {
      s[0][r] = __expf(s[0][r] - mrun[r]);
      s[1][r] = __expf(s[1][r] - mrun[r]);
      s[2][r] = __expf(s[2][r] - mrun[r]);
      s[3][r] = __expf(s[3][r] - mrun[r]);
      float sum = s[0][r] + s[1][r] + s[2][r] + s[3][r];
#pragma unroll
      for (int off = 1; off < 16; off <<= 1) sum += __shfl_xor(sum, off);
      lrun[r] = lrun[r] * al[r] + sum;
    }
    const f32x4 alv = {al[0], al[1], al[2], al[3]};
#pragma unroll
    for (int t = 0; t < 4; ++t) o[t] *= alv;

    // P -> per-wave LDS tile [16 q][64 k] (swizzled), then read A-fragments
    char* Pw = (char*)&Pl[wid][0];
#pragma unroll
    for (int kk = 0; kk < 4; ++kk)
#pragma unroll
      for (int r = 0; r < 4; ++r) {
        const int row = lg * 4 + r;
        *(u16*)(Pw + row * 128 + (((kk * 16 + li) * 2) ^ ((row & 7) << 4))) =
            f2bf(s[kk][r]);
      }
    asm volatile("s_waitcnt lgkmcnt(0)" ::: "memory");

    bf16x8 pa0, pa1;
    {
      const char* pb = Pw + li * 128;
      const int sw = (li & 7) << 4;
      pa0 = *(const bf16x8_ma*)(pb + ((lg * 16) ^ sw));
      pa1 = *(const bf16x8_ma*)(pb + ((64 + lg * 16) ^ sw));
    }
#pragma unroll
    for (int t = 0; t < 4; ++t) {
      const int row = t * 16 + li;
      const char* vb = (const char*)VTl + row * 128;
      const int sw = (row & 7) << 4;
      bf16x8 v0 = *(const bf16x8_ma*)(vb + ((lg * 16) ^ sw));
      bf16x8 v1 = *(const bf16x8_ma*)(vb + ((64 + lg * 16) ^ sw));
      o[t] = __builtin_amdgcn_mfma_f32_16x16x32_bf16(pa0, v0, o[t], 0, 0, 0);
      o[t] = __builtin_amdgcn_mfma_f32_16x16x32_bf16(pa1, v1, o[t], 0, 0, 0);
    }
  }

#pragma unroll
  for (int r = 0; r < 4; ++r) {
    const float inv = 1.f / lrun[r];
    const int q = qb * 64 + wid * 16 + lg * 4 + r;
    u16* op = Og + bbase + (size_t)q * D_ + hoff + li;
#pragma unroll
    for (int t = 0; t < 4; ++t) op[t * 16] = f2bf(o[t][r] * inv);
  }
}

// ---------------------------------------------------------------------------
// R5 golden slow path — retained as fallback for small-ws worlds.
// ---------------------------------------------------------------------------
template <bool A_SCR, bool SCR_F32, bool OUT_FINAL>
__global__ __launch_bounds__(256) void proj_slow(
    const void* __restrict__ Ag, const u16* __restrict__ Wg,
    void* __restrict__ Cg) {
  const bool det = detect_f32(Wg);
  const bool a_f32 = A_SCR ? SCR_F32 : det;
  const int m = blockIdx.x;
  const int n = blockIdx.y * 256 + threadIdx.x;
  const size_t arow = (size_t)m * D_;
  const size_t wrow = (size_t)n * D_;
  float acc = 0.f;
  for (int k = 0; k < D_; ++k) {
    float a = a_f32 ? ((const f32_ma*)Ag)[arow + k]
                    : bf2f(((const u16_ma*)Ag)[arow + k]);
    float w = det ? ((const f32_ma*)Wg)[wrow + k]
                  : bf2f(((const u16_ma*)Wg)[wrow + k]);
    acc += a * w;
  }
  const size_t ci = (size_t)m * D_ + n;
  const bool c_f32 = OUT_FINAL ? det : SCR_F32;
  if (c_f32)
    ((f32_ma*)Cg)[ci] = acc;
  else
    ((u16_ma*)Cg)[ci] = f2bf(acc);
}

template <bool SCR_F32>
__global__ __launch_bounds__(256) void attn_slow(
    const void* __restrict__ Qg, const void* __restrict__ Kg,
    const void* __restrict__ Vg, void* __restrict__ Cg) {
  const int tid = threadIdx.x;
  const int qblk = blockIdx.x & 7;
  const int h = (blockIdx.x >> 3) & 15;
  const int b = blockIdx.x >> 7;
  const int q = qblk * 256 + tid;
  const size_t base = (size_t)b * S_ * D_;
  const int hoff = h * HD_;

  float qv[64];
  {
    const size_t qrow = base + (size_t)q * D_ + hoff;
    for (int d = 0; d < 64; ++d)
      qv[d] = SCR_F32 ? ((const f32_ma*)Qg)[qrow + d]
                      : bf2f(((const u16_ma*)Qg)[qrow + d]);
  }
  float o[64];
  for (int d = 0; d < 64; ++d) o[d] = 0.f;
  float m = -1e30f, l = 0.f;
  for (int key = 0; key < S_; ++key) {
    const size_t krow = base + (size_t)key * D_ + hoff;
    float s = 0.f;
    for (int d = 0; d < 64; ++d) {
      float kx = SCR_F32 ? ((const f32_ma*)Kg)[krow + d]
                         : bf2f(((const u16_ma*)Kg)[krow + d]);
      s += qv[d] * kx;
    }
    s *= 0.125f;
    float mn = fmaxf(m, s);
    float al = expf(m - mn);
    float pe = expf(s - mn);
    m = mn;
    l = l * al + pe;
    for (int d = 0; d < 64; ++d) {
      float vx = SCR_F32 ? ((const f32_ma*)Vg)[krow + d]
                         : bf2f(((const u16_ma*)Vg)[krow + d]);
      o[d] = o[d] * al + pe * vx;
    }
  }
  const float il = 1.f / l;
  const size_t crow = base + (size_t)q * D_ + hoff;
  for (int d = 0; d < 64; ++d) {
    if (SCR_F32)
      ((f32_ma*)Cg)[crow + d] = o[d] * il;
    else
      ((u16_ma*)Cg)[crow + d] = f2bf(o[d] * il);
  }
}

extern "C" void kernel_launch(void* const* d_in, const int* in_sizes, int n_in,
                              void* d_out, int out_size, void* d_ws,
                              size_t ws_size, hipStream_t stream) {
  const u16* Wdet = (const u16*)d_in[3];  // pristine Wq for dtype detect
  const size_t NE = (size_t)B_ * S_ * D_;  // 4194304
  dim3 blk(256);

  if (ws_size >= 4 * NE * sizeof(u16)) {
    // bf16 scratch in d_ws: Qp, Kp, Vp, Xp (33.5 MB; harness gives >=64 MB)
    u16* Qp = (u16*)d_ws;
    u16* Kp = Qp + NE;
    u16* Vp = Kp + NE;
    u16* Xp = Vp + NE;
    dim3 gp(32, 8);  // (M/128, N/128)
    proj_mfma<false, false><<<gp, blk, 0, stream>>>(d_in[0], d_in[3], Qp, Wdet);
    proj_mfma<false, false><<<gp, blk, 0, stream>>>(d_in[1], d_in[4], Kp, Wdet);
    proj_mfma<false, false><<<gp, blk, 0, stream>>>(d_in[2], d_in[5], Vp, Wdet);
    attn_mfma<<<dim3(B_ * H_ * (S_ / 64)), blk, 0, stream>>>(Qp, Kp, Vp, Xp);
    proj_mfma<true, true><<<gp, blk, 0, stream>>>(Xp, d_in[6], d_out, Wdet);
  } else {
    // fallback: R5 slow path, bf16 scratch in recycled buffers
    dim3 gproj(B_ * S_, D_ / 256);
    dim3 gattn(B_ * H_ * (S_ / 256));
    u16* Qp = (u16*)d_out;
    u16* Kp = (u16*)d_in[0];
    u16* Vp = (u16*)d_in[1];
    u16* Xp = (u16*)d_in[2];
    proj_slow<false, false, false><<<gproj, blk, 0, stream>>>(d_in[0], (const u16*)d_in[3], Qp);
    proj_slow<false, false, false><<<gproj, blk, 0, stream>>>(d_in[1], (const u16*)d_in[4], Kp);
    proj_slow<false, false, false><<<gproj, blk, 0, stream>>>(d_in[2], (const u16*)d_in[5], Vp);
    attn_slow<false><<<gattn, blk, 0, stream>>>(Qp, Kp, Vp, Xp);
    proj_slow<true, false, true><<<gproj, blk, 0, stream>>>(Xp, (const u16*)d_in[6], d_out);
  }
}

// Round 2
// 283.930 us; speedup vs baseline: 134.7753x; 1.6745x over previous
//
#include <hip/hip_runtime.h>
#include <hip/hip_bf16.h>
#include <cstdint>

// R7: overhead attack.
//  - convert_bf16: one pass fp32->bf16 (or copy) for 3 inputs + 4 weights.
//  - proj_g: m97-structure GEMM with global_load_lds width-16 staging,
//    QKV fused via blockIdx.z (768 blocks = 3/CU). BN templated (128 QKV,
//    64 for output proj -> 512 blocks = 2/CU).
//  - attn_mfma2: 32 q-rows/wave (512 blocks), T14 async-stage split
//    (load t+1 regs before compute, LDS-write after barrier), T1 XCD swizzle.
// R6 post-mortem: proj was 333us at 1 block/CU + reg-staged fp32 convert;
// attn 142us with MfmaUtil 10% (scalar staging + no overlap).

#define B_ 2
#define S_ 2048
#define D_ 1024
#define H_ 16
#define HD_ 64
#define NE_ (B_ * S_ * D_)  // 4194304
#define WN_ (D_ * D_)       // 1048576

typedef unsigned short u16;
typedef unsigned int u32;
typedef u16 __attribute__((may_alias)) u16_ma;
typedef float __attribute__((may_alias)) f32_ma;
typedef u32 v4u __attribute__((ext_vector_type(4)));
typedef v4u __attribute__((may_alias)) v4u_ma;
typedef short bf16x8 __attribute__((ext_vector_type(8)));
typedef bf16x8 __attribute__((may_alias)) bf16x8_ma;
typedef float f32x4 __attribute__((ext_vector_type(4)));

__device__ __forceinline__ float bf2f(u16 u) {
  u32 x = ((u32)u) << 16;
  return __builtin_bit_cast(float, x);
}
__device__ __forceinline__ u16 f2bf(float f) {
  __hip_bfloat16 h = __float2bfloat16(f);
  return __builtin_bit_cast(u16, h);
}
__device__ __forceinline__ u32 pk2(u32 alo, u32 ahi) {
  return (u32)f2bf(__builtin_bit_cast(float, alo)) |
         ((u32)f2bf(__builtin_bit_cast(float, ahi)) << 16);
}

// async global->LDS, 16B per lane. LDS dest must be wave-uniform base;
// HW writes lane i at base + i*16 (CK-style addrspace casts).
__device__ __forceinline__ void gl_lds16(const u16* g, u16* l) {
  auto gp = (const __attribute__((address_space(1))) unsigned int*)(const void*)g;
  auto lp = (__attribute__((address_space(3))) unsigned int*)(void*)l;
  __builtin_amdgcn_global_load_lds(gp, lp, 16, 0, 0);
}

// Input dtype detect (R5/R6-verified): scan first 2048 u16 of pristine Wq.
__device__ __forceinline__ bool detect_f32(const u16* Wg) {
  const int lane = threadIdx.x & 63;
  bool hit = false;
#pragma unroll
  for (int i = 0; i < 4; ++i) {
    v4u u = *(const v4u_ma*)(Wg + lane * 32 + i * 8);
#pragma unroll
    for (int j = 0; j < 4; ++j) {
      u32 w = u[j];
      hit |= (((w >> 7) & 0xFFu) >= 0xF0u) || (((w >> 23) & 0xFFu) >= 0xF0u);
    }
  }
  return __any(hit);
}

// ---------------------------------------------------------------------------
// Convert all 7 input buffers to bf16 scratch (copy if already bf16).
// grid (2048, 7): y = buffer id (0-2 inputs, 3-6 weights). 8 elems/thread.
// ---------------------------------------------------------------------------
__global__ __launch_bounds__(256) void convert_bf16(
    const void* s0, const void* s1, const void* s2, const void* s3,
    const void* s4, const void* s5, const void* s6, u16* __restrict__ dst_in,
    u16* __restrict__ dst_w, const u16* __restrict__ Wdet) {
  const bool det = detect_f32(Wdet);
  const int y = blockIdx.y;
  const void* src;
  u16* dst;
  int n;
  if (y < 3) {
    src = (y == 0) ? s0 : ((y == 1) ? s1 : s2);
    dst = dst_in + (size_t)y * NE_;
    n = NE_;
  } else {
    src = (y == 3) ? s3 : ((y == 4) ? s4 : ((y == 5) ? s5 : s6));
    dst = dst_w + (size_t)(y - 3) * WN_;
    n = WN_;
  }
  const int i = (blockIdx.x * 256 + threadIdx.x) * 8;
  if (i >= n) return;
  v4u out;
  if (det) {
    const v4u_ma* fp = (const v4u_ma*)((const float*)src + i);
    v4u f0 = fp[0], f1 = fp[1];
    out[0] = pk2(f0[0], f0[1]);
    out[1] = pk2(f0[2], f0[3]);
    out[2] = pk2(f1[0], f1[1]);
    out[3] = pk2(f1[2], f1[3]);
  } else {
    out = *(const v4u_ma*)((const u16*)src + i);
  }
  *(v4u_ma*)(dst + i) = out;
}

// ---------------------------------------------------------------------------
// C[4096, 1024] = A[4096,1024] @ W[1024,1024]^T, all-bf16 inputs.
// BM=128, BK=32, BN templated. 4 waves (2x2). global_load_lds staging
// (m97 2-barrier structure). blockIdx.z strides A/W/C for fused QKV.
// ---------------------------------------------------------------------------
template <int BN, bool OUT_DET>
__global__ __launch_bounds__(256) void proj_g(
    const u16* __restrict__ Ab, const u16* __restrict__ Wb,
    void* __restrict__ Cb, const u16* __restrict__ Wdet) {
  __shared__ u16 Al[128 * 32];
  __shared__ u16 Wl[BN * 32];

  const bool outf32 = OUT_DET ? detect_f32(Wdet) : false;

  const int tid = threadIdx.x;
  const int lane = tid & 63, wid = tid >> 6;
  const int lg = lane >> 4, li = lane & 15;
  const int wr = wid >> 1, wc = wid & 1;
  const int z = blockIdx.z;
  const u16* Ag = Ab + (size_t)z * NE_;
  const u16* Wg = Wb + (size_t)z * WN_;
  const int m0 = blockIdx.x * 128, n0 = blockIdx.y * BN;

  // staging: lane covers row (wid*16 + lane/4) [+p*64], col (lane&3)*8
  const int srow = wid * 16 + (lane >> 2);
  const int scol = (lane & 3) * 8;
  const u16* Asrc = Ag + (size_t)(m0 + srow) * D_ + scol;
  const u16* Wsrc = Wg + (size_t)(n0 + srow) * D_ + scol;
  u16* Adst = Al + (wid * 16) * 32;  // wave-uniform
  u16* Wdst = Wl + (wid * 16) * 32;

  constexpr int NF = BN / 32;
  f32x4 acc[4][NF];
#pragma unroll
  for (int m = 0; m < 4; ++m)
#pragma unroll
    for (int n = 0; n < NF; ++n) acc[m][n] = (f32x4){0.f, 0.f, 0.f, 0.f};

  for (int kt = 0; kt < 32; ++kt) {
    const int k0 = kt * 32;
    __syncthreads();
    gl_lds16(Asrc + k0, Adst);
    gl_lds16(Asrc + (size_t)64 * D_ + k0, Adst + 64 * 32);
    gl_lds16(Wsrc + k0, Wdst);
    if constexpr (BN == 128) gl_lds16(Wsrc + (size_t)64 * D_ + k0, Wdst + 64 * 32);
    __syncthreads();

    bf16x8 af[4], bw[NF];
#pragma unroll
    for (int m = 0; m < 4; ++m)
      af[m] = *(const bf16x8_ma*)(Al + (wr * 64 + m * 16 + li) * 32 + lg * 8);
#pragma unroll
    for (int n = 0; n < NF; ++n)
      bw[n] =
          *(const bf16x8_ma*)(Wl + (wc * (BN / 2) + n * 16 + li) * 32 + lg * 8);
#pragma unroll
    for (int m = 0; m < 4; ++m)
#pragma unroll
      for (int n = 0; n < NF; ++n)
        acc[m][n] =
            __builtin_amdgcn_mfma_f32_16x16x32_bf16(af[m], bw[n], acc[m][n], 0, 0, 0);
  }

#pragma unroll
  for (int m = 0; m < 4; ++m)
#pragma unroll
    for (int n = 0; n < NF; ++n)
#pragma unroll
      for (int r = 0; r < 4; ++r) {
        const int row = m0 + wr * 64 + m * 16 + lg * 4 + r;
        const int col = n0 + wc * (BN / 2) + n * 16 + li;
        const size_t idx = (size_t)row * D_ + col;
        const float v = acc[m][n][r];
        if (OUT_DET) {
          if (outf32)
            ((f32_ma*)Cb)[idx] = v;
          else
            ((u16_ma*)Cb)[idx] = f2bf(v);
        } else {
          ((u16_ma*)((u16*)Cb + (size_t)z * NE_))[idx] = f2bf(v);
        }
      }
}

// ---------------------------------------------------------------------------
// Flash attention v2. 4 waves x 32 q-rows = 128 q/block, 512 blocks.
// 64-key tiles; K + V^T in LDS (XOR-swizzled 128B rows); async-stage split;
// XCD-swizzled blockIdx. Softmax rows on 16-lane groups (R6-verified math).
// ---------------------------------------------------------------------------
__global__ __launch_bounds__(256) void attn_mfma2(
    const u16* __restrict__ Qg, const u16* __restrict__ Kg,
    const u16* __restrict__ Vg, u16* __restrict__ Og) {
  __shared__ u16 Kl[64 * 64];
  __shared__ u16 VTl[64 * 64];
  __shared__ u16 Pl[4][32 * 64];

  const int tid = threadIdx.x;
  const int wid = tid >> 6, lane = tid & 63;
  const int lg = lane >> 4, li = lane & 15;

  // T1 XCD swizzle (nwg=512, divisible by 8): 64 consecutive per XCD share K/V
  const int bid = blockIdx.x;
  const int swz = (bid & 7) * 64 + (bid >> 3);
  const int qb = swz & 15;
  const int h = (swz >> 4) & 15;
  const int b = swz >> 8;
  const size_t bbase = (size_t)b * S_ * D_;
  const int hoff = h * HD_;
  const int q0 = qb * 128 + wid * 32;

  // Q A-fragments: aq[qf][c] -> Q[q0+qf*16+li][c*32 + lg*8 + j]
  bf16x8 aq[2][2];
#pragma unroll
  for (int qf = 0; qf < 2; ++qf) {
    const u16* qp =
        Qg + bbase + (size_t)(q0 + qf * 16 + li) * D_ + hoff + lg * 8;
    aq[qf][0] = *(const bf16x8_ma*)(qp);
    aq[qf][1] = *(const bf16x8_ma*)(qp + 32);
  }

  f32x4 o[2][4];
  float mrun[2][4], lrun[2][4];
#pragma unroll
  for (int qf = 0; qf < 2; ++qf)
#pragma unroll
    for (int t = 0; t < 4; ++t) {
      o[qf][t] = (f32x4){0.f, 0.f, 0.f, 0.f};
      mrun[qf][t] = -1e30f;
      lrun[qf][t] = 0.f;
    }

  const int krr = tid >> 3;       // K-stage row (+32), 8 lanes/row
  const int kc8 = (tid & 7) * 8;  // K-stage col
  const int vkr = lane;           // V-stage key row
  const int vd0 = wid * 8;        // V-stage d base (+32)

  v4u kr0, kr1, vr0, vr1;
  auto kv_load = [&](int kt) {
    const int key0 = kt * 64;
    kr0 = *(const v4u_ma*)(Kg + bbase + (size_t)(key0 + krr) * D_ + hoff + kc8);
    kr1 = *(const v4u_ma*)(Kg + bbase + (size_t)(key0 + 32 + krr) * D_ + hoff + kc8);
    vr0 = *(const v4u_ma*)(Vg + bbase + (size_t)(key0 + vkr) * D_ + hoff + vd0);
    vr1 = *(const v4u_ma*)(Vg + bbase + (size_t)(key0 + vkr) * D_ + hoff + vd0 + 32);
  };
  auto kv_write = [&]() {
    const int ksw = (krr & 7) << 4;
    *(v4u_ma*)((char*)Kl + krr * 128 + ((kc8 * 2) ^ ksw)) = kr0;
    *(v4u_ma*)((char*)Kl + (32 + krr) * 128 + ((kc8 * 2) ^ ksw)) = kr1;
    union {
      v4u v;
      u16 e[8];
    } uu;
    uu.v = vr0;
#pragma unroll
    for (int j = 0; j < 8; ++j) {
      const int d = vd0 + j;
      *(u16*)((char*)VTl + d * 128 + ((vkr * 2) ^ ((d & 7) << 4))) = uu.e[j];
    }
    uu.v = vr1;
#pragma unroll
    for (int j = 0; j < 8; ++j) {
      const int d = vd0 + 32 + j;
      *(u16*)((char*)VTl + d * 128 + ((vkr * 2) ^ ((d & 7) << 4))) = uu.e[j];
    }
  };

  kv_load(0);
  kv_write();

  for (int kt = 0; kt < S_ / 64; ++kt) {
    __syncthreads();  // staged tile kt visible
    if (kt < S_ / 64 - 1) kv_load(kt + 1);  // T14: issue next loads early

    // QK^T: s[qf][kk], C-layout row=lg*4+r, col=li
    f32x4 s[2][4];
#pragma unroll
    for (int kk = 0; kk < 4; ++kk) {
      const int row = kk * 16 + li;
      const char* kb = (const char*)Kl + row * 128;
      const int sw = (row & 7) << 4;
      bf16x8 b0 = *(const bf16x8_ma*)(kb + ((lg * 16) ^ sw));
      bf16x8 b1 = *(const bf16x8_ma*)(kb + ((64 + lg * 16) ^ sw));
#pragma unroll
      for (int qf = 0; qf < 2; ++qf) {
        f32x4 z = (f32x4){0.f, 0.f, 0.f, 0.f};
        z = __builtin_amdgcn_mfma_f32_16x16x32_bf16(aq[qf][0], b0, z, 0, 0, 0);
        z = __builtin_amdgcn_mfma_f32_16x16x32_bf16(aq[qf][1], b1, z, 0, 0, 0);
        s[qf][kk] = z * 0.125f;
      }
    }

    // online softmax (rows live on 16-lane groups)
#pragma unroll
    for (int qf = 0; qf < 2; ++qf) {
      float al[4];
#pragma unroll
      for (int r = 0; r < 4; ++r) {
        float t0 =
            fmaxf(fmaxf(s[qf][0][r], s[qf][1][r]), fmaxf(s[qf][2][r], s[qf][3][r]));
#pragma unroll
        for (int off = 1; off < 16; off <<= 1) t0 = fmaxf(t0, __shfl_xor(t0, off));
        const float mn = fmaxf(mrun[qf][r], t0);
        al[r] = __expf(mrun[qf][r] - mn);
        mrun[qf][r] = mn;
      }
#pragma unroll
      for (int r = 0; r < 4; ++r) {
        s[qf][0][r] = __expf(s[qf][0][r] - mrun[qf][r]);
        s[qf][1][r] = __expf(s[qf][1][r] - mrun[qf][r]);
        s[qf][2][r] = __expf(s[qf][2][r] - mrun[qf][r]);
        s[qf][3][r] = __expf(s[qf][3][r] - mrun[qf][r]);
        float sum = s[qf][0][r] + s[qf][1][r] + s[qf][2][r] + s[qf][3][r];
#pragma unroll
        for (int off = 1; off < 16; off <<= 1) sum += __shfl_xor(sum, off);
        lrun[qf][r] = lrun[qf][r] * al[r] + sum;
      }
      const f32x4 alv = {al[0], al[1], al[2], al[3]};
#pragma unroll
      for (int t = 0; t < 4; ++t) o[qf][t] *= alv;
    }

    // P -> per-wave LDS (swizzled), then A-fragments
    char* Pw = (char*)&Pl[wid][0];
#pragma unroll
    for (int qf = 0; qf < 2; ++qf)
#pragma unroll
      for (int kk = 0; kk < 4; ++kk)
#pragma unroll
        for (int r = 0; r < 4; ++r) {
          const int row = qf * 16 + lg * 4 + r;
          *(u16*)(Pw + row * 128 + (((kk * 16 + li) * 2) ^ ((row & 7) << 4))) =
              f2bf(s[qf][kk][r]);
        }
    asm volatile("s_waitcnt lgkmcnt(0)" ::: "memory");

    bf16x8 pa[2][2];
#pragma unroll
    for (int qf = 0; qf < 2; ++qf) {
      const char* pb = Pw + (qf * 16 + li) * 128;
      const int sw = (li & 7) << 4;
      pa[qf][0] = *(const bf16x8_ma*)(pb + ((lg * 16) ^ sw));
      pa[qf][1] = *(const bf16x8_ma*)(pb + ((64 + lg * 16) ^ sw));
    }

    // PV: V frags shared across qf
#pragma unroll
    for (int t = 0; t < 4; ++t) {
      const int row = t * 16 + li;
      const char* vb = (const char*)VTl + row * 128;
      const int sw = (row & 7) << 4;
      bf16x8 v0 = *(const bf16x8_ma*)(vb + ((lg * 16) ^ sw));
      bf16x8 v1 = *(const bf16x8_ma*)(vb + ((64 + lg * 16) ^ sw));
#pragma unroll
      for (int qf = 0; qf < 2; ++qf) {
        o[qf][t] =
            __builtin_amdgcn_mfma_f32_16x16x32_bf16(pa[qf][0], v0, o[qf][t], 0, 0, 0);
        o[qf][t] =
            __builtin_amdgcn_mfma_f32_16x16x32_bf16(pa[qf][1], v1, o[qf][t], 0, 0, 0);
      }
    }

    __syncthreads();  // all waves done reading Kl/VTl
    if (kt < S_ / 64 - 1) kv_write();  // T14: write next tile late
  }

#pragma unroll
  for (int qf = 0; qf < 2; ++qf)
#pragma unroll
    for (int r = 0; r < 4; ++r) {
      const float inv = 1.f / lrun[qf][r];
      const int q = q0 + qf * 16 + lg * 4 + r;
      u16* op = Og + bbase + (size_t)q * D_ + hoff + li;
#pragma unroll
      for (int t = 0; t < 4; ++t) op[t * 16] = f2bf(o[qf][t][r] * inv);
    }
}

// ---------------------------------------------------------------------------
// R5 golden slow path — fallback for small-ws worlds (never hit in practice).
// ---------------------------------------------------------------------------
template <bool A_SCR, bool SCR_F32, bool OUT_FINAL>
__global__ __launch_bounds__(256) void proj_slow(
    const void* __restrict__ Ag, const u16* __restrict__ Wg,
    void* __restrict__ Cg) {
  const bool det = detect_f32(Wg);
  const bool a_f32 = A_SCR ? SCR_F32 : det;
  const int m = blockIdx.x;
  const int n = blockIdx.y * 256 + threadIdx.x;
  const size_t arow = (size_t)m * D_;
  const size_t wrow = (size_t)n * D_;
  float acc = 0.f;
  for (int k = 0; k < D_; ++k) {
    float a = a_f32 ? ((const f32_ma*)Ag)[arow + k]
                    : bf2f(((const u16_ma*)Ag)[arow + k]);
    float w = det ? ((const f32_ma*)Wg)[wrow + k]
                  : bf2f(((const u16_ma*)Wg)[wrow + k]);
    acc += a * w;
  }
  const size_t ci = (size_t)m * D_ + n;
  const bool c_f32 = OUT_FINAL ? det : SCR_F32;
  if (c_f32)
    ((f32_ma*)Cg)[ci] = acc;
  else
    ((u16_ma*)Cg)[ci] = f2bf(acc);
}

template <bool SCR_F32>
__global__ __launch_bounds__(256) void attn_slow(
    const void* __restrict__ Qg, const void* __restrict__ Kg,
    const void* __restrict__ Vg, void* __restrict__ Cg) {
  const int tid = threadIdx.x;
  const int qblk = blockIdx.x & 7;
  const int h = (blockIdx.x >> 3) & 15;
  const int b = blockIdx.x >> 7;
  const int q = qblk * 256 + tid;
  const size_t base = (size_t)b * S_ * D_;
  const int hoff = h * HD_;
  float qv[64];
  {
    const size_t qrow = base + (size_t)q * D_ + hoff;
    for (int d = 0; d < 64; ++d)
      qv[d] = SCR_F32 ? ((const f32_ma*)Qg)[qrow + d]
                      : bf2f(((const u16_ma*)Qg)[qrow + d]);
  }
  float o[64];
  for (int d = 0; d < 64; ++d) o[d] = 0.f;
  float m = -1e30f, l = 0.f;
  for (int key = 0; key < S_; ++key) {
    const size_t krow = base + (size_t)key * D_ + hoff;
    float s = 0.f;
    for (int d = 0; d < 64; ++d) {
      float kx = SCR_F32 ? ((const f32_ma*)Kg)[krow + d]
                         : bf2f(((const u16_ma*)Kg)[krow + d]);
      s += qv[d] * kx;
    }
    s *= 0.125f;
    float mn = fmaxf(m, s);
    float al = expf(m - mn);
    float pe = expf(s - mn);
    m = mn;
    l = l * al + pe;
    for (int d = 0; d < 64; ++d) {
      float vx = SCR_F32 ? ((const f32_ma*)Vg)[krow + d]
                         : bf2f(((const u16_ma*)Vg)[krow + d]);
      o[d] = o[d] * al + pe * vx;
    }
  }
  const float il = 1.f / l;
  const size_t crow = base + (size_t)q * D_ + hoff;
  for (int d = 0; d < 64; ++d) {
    if (SCR_F32)
      ((f32_ma*)Cg)[crow + d] = o[d] * il;
    else
      ((u16_ma*)Cg)[crow + d] = f2bf(o[d] * il);
  }
}

extern "C" void kernel_launch(void* const* d_in, const int* in_sizes, int n_in,
                              void* d_out, int out_size, void* d_ws,
                              size_t ws_size, hipStream_t stream) {
  const u16* Wdet = (const u16*)d_in[3];  // pristine Wq for dtype detect
  dim3 blk(256);

  // ws layout (bytes): 3*NE*2 (conv inputs) + 4*WN*2 (conv weights)
  //                  + 3*NE*2 (Q/K/V proj) + NE*2 (attn out) = 64 MiB exactly.
  if (ws_size >= (size_t)4 * NE_ * sizeof(float)) {
    u16* Qi = (u16*)d_ws;
    u16* Wc = Qi + (size_t)3 * NE_;
    u16* Qp = Wc + (size_t)4 * WN_;
    u16* Xp = Qp + (size_t)3 * NE_;

    convert_bf16<<<dim3(2048, 7), blk, 0, stream>>>(
        d_in[0], d_in[1], d_in[2], d_in[3], d_in[4], d_in[5], d_in[6], Qi, Wc,
        Wdet);
    proj_g<128, false><<<dim3(32, 8, 3), blk, 0, stream>>>(Qi, Wc, Qp, Wdet);
    attn_mfma2<<<dim3(512), blk, 0, stream>>>(Qp, Qp + NE_, Qp + (size_t)2 * NE_,
                                              Xp);
    proj_g<64, true><<<dim3(32, 16, 1), blk, 0, stream>>>(
        Xp, Wc + (size_t)3 * WN_, d_out, Wdet);
  } else {
    // fallback: R5 scalar slow path, bf16 scratch in recycled buffers
    dim3 gproj(B_ * S_, D_ / 256);
    dim3 gattn(B_ * H_ * (S_ / 256));
    u16* Qp = (u16*)d_out;
    u16* Kp = (u16*)d_in[0];
    u16* Vp = (u16*)d_in[1];
    u16* Xp = (u16*)d_in[2];
    proj_slow<false, false, false><<<gproj, blk, 0, stream>>>(
        d_in[0], (const u16*)d_in[3], Qp);
    proj_slow<false, false, false><<<gproj, blk, 0, stream>>>(
        d_in[1], (const u16*)d_in[4], Kp);
    proj_slow<false, false, false><<<gproj, blk, 0, stream>>>(
        d_in[2], (const u16*)d_in[5], Vp);
    attn_slow<false><<<gattn, blk, 0, stream>>>(Qp, Kp, Vp, Xp);
    proj_slow<true, false, true><<<gproj, blk, 0, stream>>>(
        Xp, (const u16*)d_in[6], d_out);
  }
}

// Round 3
// 228.912 us; speedup vs baseline: 167.1679x; 1.2403x over previous
//
#include <hip/hip_runtime.h>
#include <hip/hip_bf16.h>

// R8: attention restructured to m214-style swapped-operand 32x32 MFMA
// (S^T = K Q^T, O^T = V^T P^T) -> q lane-local, softmax in-register,
// P exchanged via shfl_xor(32) (no LDS round-trip). Staging kept verbatim
// from R7 (verified). Proj: BK=64 + XOR-swizzled LDS (pre-swizzled gl_lds
// source). 1/8 scale folded into Q-projection (exact).

#define B_ 2
#define S_ 2048
#define D_ 1024
#define H_ 16
#define HD_ 64
#define NE_ (B_ * S_ * D_)  // 4194304
#define WN_ (D_ * D_)       // 1048576

typedef unsigned short u16;
typedef unsigned int u32;
typedef u16 __attribute__((may_alias)) u16_ma;
typedef float __attribute__((may_alias)) f32_ma;
typedef u32 v4u __attribute__((ext_vector_type(4)));
typedef v4u __attribute__((may_alias)) v4u_ma;
typedef short bf16x8 __attribute__((ext_vector_type(8)));
typedef bf16x8 __attribute__((may_alias)) bf16x8_ma;
typedef float f32x4 __attribute__((ext_vector_type(4)));
typedef float f32x16 __attribute__((ext_vector_type(16)));

__device__ __forceinline__ float bf2f(u16 u) {
  u32 x = ((u32)u) << 16;
  return __builtin_bit_cast(float, x);
}
__device__ __forceinline__ u16 f2bf(float f) {
  __hip_bfloat16 h = __float2bfloat16(f);
  return __builtin_bit_cast(u16, h);
}
__device__ __forceinline__ u32 pk2(u32 alo, u32 ahi) {
  return (u32)f2bf(__builtin_bit_cast(float, alo)) |
         ((u32)f2bf(__builtin_bit_cast(float, ahi)) << 16);
}
__device__ __forceinline__ u32 pkf(float lo, float hi) {
  return (u32)f2bf(lo) | ((u32)f2bf(hi) << 16);
}

// async global->LDS, 16B/lane; dest = wave-uniform base + lane*16 (m104).
__device__ __forceinline__ void gl_lds16(const u16* g, u16* l) {
  auto gp = (const __attribute__((address_space(1))) unsigned int*)(const void*)g;
  auto lp = (__attribute__((address_space(3))) unsigned int*)(void*)l;
  __builtin_amdgcn_global_load_lds(gp, lp, 16, 0, 0);
}

// Input dtype detect (R5-R7 harness-verified).
__device__ __forceinline__ bool detect_f32(const u16* Wg) {
  const int lane = threadIdx.x & 63;
  bool hit = false;
#pragma unroll
  for (int i = 0; i < 4; ++i) {
    v4u u = *(const v4u_ma*)(Wg + lane * 32 + i * 8);
#pragma unroll
    for (int j = 0; j < 4; ++j) {
      u32 w = u[j];
      hit |= (((w >> 7) & 0xFFu) >= 0xF0u) || (((w >> 23) & 0xFFu) >= 0xF0u);
    }
  }
  return __any(hit);
}

// ---------------------------------------------------------------------------
// Convert all 7 input buffers to bf16 scratch (copy if already bf16).
// ---------------------------------------------------------------------------
__global__ __launch_bounds__(256) void convert_bf16(
    const void* s0, const void* s1, const void* s2, const void* s3,
    const void* s4, const void* s5, const void* s6, u16* __restrict__ dst_in,
    u16* __restrict__ dst_w, const u16* __restrict__ Wdet) {
  const bool det = detect_f32(Wdet);
  const int y = blockIdx.y;
  const void* src;
  u16* dst;
  int n;
  if (y < 3) {
    src = (y == 0) ? s0 : ((y == 1) ? s1 : s2);
    dst = dst_in + (size_t)y * NE_;
    n = NE_;
  } else {
    src = (y == 3) ? s3 : ((y == 4) ? s4 : ((y == 5) ? s5 : s6));
    dst = dst_w + (size_t)(y - 3) * WN_;
    n = WN_;
  }
  const int i = (blockIdx.x * 256 + threadIdx.x) * 8;
  if (i >= n) return;
  v4u out;
  if (det) {
    const v4u_ma* fp = (const v4u_ma*)((const float*)src + i);
    v4u f0 = fp[0], f1 = fp[1];
    out[0] = pk2(f0[0], f0[1]);
    out[1] = pk2(f0[2], f0[3]);
    out[2] = pk2(f1[0], f1[1]);
    out[3] = pk2(f1[2], f1[3]);
  } else {
    out = *(const v4u_ma*)((const u16*)src + i);
  }
  *(v4u_ma*)(dst + i) = out;
}

// ---------------------------------------------------------------------------
// C[4096,1024] = A @ W^T, all-bf16. BM=128, BK=64, BN templated.
// XOR-swizzled LDS rows (128B): staged via pre-swizzled gl_lds SOURCE
// (linear dest, rule #21), read with matching XOR. blockIdx.z fuses QKV.
// z==0 (Q) epilogue folds the 1/sqrt(HD)=0.125 scale (exact in bf16).
// ---------------------------------------------------------------------------
template <int BN, bool OUT_DET>
__global__ __launch_bounds__(256) void proj_g(
    const u16* __restrict__ Ab, const u16* __restrict__ Wb,
    void* __restrict__ Cb, const u16* __restrict__ Wdet) {
  __shared__ u16 Al[128 * 64];
  __shared__ u16 Wl[BN * 64];

  const bool outf32 = OUT_DET ? detect_f32(Wdet) : false;

  const int tid = threadIdx.x;
  const int lane = tid & 63, wid = tid >> 6;
  const int lg = lane >> 4, li = lane & 15;
  const int wr = wid >> 1, wc = wid & 1;
  const int z = blockIdx.z;
  const char* Ag = (const char*)(Ab + (size_t)z * NE_);
  const char* Wg = (const char*)(Wb + (size_t)z * WN_);
  const int m0 = blockIdx.x * 128, n0 = blockIdx.y * BN;

  // staging: per chunk, lane covers row +lane>>3, 16B col (lane&7)*16,
  // source pre-swizzled so linear LDS + XOR-read is consistent.
  const int lr = lane >> 3;
  const int swzb = ((lane & 7) * 16) ^ (lr << 4);

  constexpr int NF = BN / 32;
  f32x4 acc[4][NF];
#pragma unroll
  for (int m = 0; m < 4; ++m)
#pragma unroll
    for (int n = 0; n < NF; ++n) acc[m][n] = (f32x4){0.f, 0.f, 0.f, 0.f};

  for (int kt = 0; kt < 16; ++kt) {
    const int k0b = kt * 128;  // byte offset along K (64 elems)
    __syncthreads();
#pragma unroll
    for (int c = 0; c < 4; ++c) {
      const int row = wid * 32 + c * 8 + lr;
      gl_lds16((const u16*)(Ag + (size_t)(m0 + row) * 2048 + k0b + swzb),
               Al + (wid * 32 + c * 8) * 64);
    }
    if constexpr (BN == 128) {
#pragma unroll
      for (int c = 0; c < 4; ++c) {
        const int row = wid * 32 + c * 8 + lr;
        gl_lds16((const u16*)(Wg + (size_t)(n0 + row) * 2048 + k0b + swzb),
                 Wl + (wid * 32 + c * 8) * 64);
      }
    } else {
#pragma unroll
      for (int c = 0; c < 2; ++c) {
        const int row = wid * 16 + c * 8 + lr;
        gl_lds16((const u16*)(Wg + (size_t)(n0 + row) * 2048 + k0b + swzb),
                 Wl + (wid * 16 + c * 8) * 64);
      }
    }
    __syncthreads();

#pragma unroll
    for (int ks = 0; ks < 2; ++ks) {
      bf16x8 af[4], bw[NF];
#pragma unroll
      for (int m = 0; m < 4; ++m) {
        const int row = wr * 64 + m * 16 + li;
        af[m] = *(const bf16x8_ma*)((const char*)Al + row * 128 +
                                    ((ks * 64 + lg * 16) ^ ((row & 7) << 4)));
      }
#pragma unroll
      for (int n = 0; n < NF; ++n) {
        const int row = wc * (BN / 2) + n * 16 + li;
        bw[n] = *(const bf16x8_ma*)((const char*)Wl + row * 128 +
                                    ((ks * 64 + lg * 16) ^ ((row & 7) << 4)));
      }
#pragma unroll
      for (int m = 0; m < 4; ++m)
#pragma unroll
        for (int n = 0; n < NF; ++n)
          acc[m][n] = __builtin_amdgcn_mfma_f32_16x16x32_bf16(af[m], bw[n],
                                                              acc[m][n], 0, 0, 0);
    }
  }

  const float zs = (!OUT_DET && z == 0) ? 0.125f : 1.0f;
#pragma unroll
  for (int m = 0; m < 4; ++m)
#pragma unroll
    for (int n = 0; n < NF; ++n)
#pragma unroll
      for (int r = 0; r < 4; ++r) {
        const int row = m0 + wr * 64 + m * 16 + lg * 4 + r;
        const int col = n0 + wc * (BN / 2) + n * 16 + li;
        const size_t idx = (size_t)row * D_ + col;
        const float v = acc[m][n][r] * zs;
        if (OUT_DET) {
          if (outf32)
            ((f32_ma*)Cb)[idx] = v;
          else
            ((u16_ma*)Cb)[idx] = f2bf(v);
        } else {
          ((u16_ma*)((u16*)Cb + (size_t)z * NE_))[idx] = f2bf(v);
        }
      }
}

// ---------------------------------------------------------------------------
// Flash attention v3: 32x32x16 MFMA, swapped operands.
//   S^T = K Q^T  (C: col=lane&31 -> q lane-local, row=key on regs)
//   O^T = V^T P^T (C: col=q, row=d) -> softmax stats per-lane scalars.
// P built in-register: pack bf16 pairs, exchange with shfl_xor(32).
// K [64k][64d] + V^T [64d][64k] XOR-swz LDS (R7-verified staging, verbatim).
// Q pre-scaled by 0.125 in proj. 4 waves x 32 q = 128 q/block, 512 blocks.
// ---------------------------------------------------------------------------
__global__ __launch_bounds__(256) void attn3(
    const u16* __restrict__ Qg, const u16* __restrict__ Kg,
    const u16* __restrict__ Vg, u16* __restrict__ Og) {
  __shared__ u16 Kl[64 * 64];
  __shared__ u16 VTl[64 * 64];

  const int tid = threadIdx.x;
  const int wid = tid >> 6, lane = tid & 63;
  const int l31 = lane & 31;
  const int hi = lane >> 5;

  // T1 XCD swizzle (512 % 8 == 0)
  const int bid = blockIdx.x;
  const int swz = (bid & 7) * 64 + (bid >> 3);
  const int qb = swz & 15;
  const int h = (swz >> 4) & 15;
  const int b = swz >> 8;
  const size_t bbase = (size_t)b * S_ * D_;
  const int hoff = h * HD_;
  const int q0w = qb * 128 + wid * 32;

  // Q B-frags: bq[dblk] -> Q[q0w+l31][hoff + dblk*16 + hi*8 + e]
  bf16x8 bq[4];
  {
    const u16* qp = Qg + bbase + (size_t)(q0w + l31) * D_ + hoff + hi * 8;
#pragma unroll
    for (int dblk = 0; dblk < 4; ++dblk)
      bq[dblk] = *(const bf16x8_ma*)(qp + dblk * 16);
  }

  f32x16 o0, o1;
#pragma unroll
  for (int i = 0; i < 16; ++i) {
    o0[i] = 0.f;
    o1[i] = 0.f;
  }
  float mrun = -1e30f, lrun = 0.f;

  // staging (R7-verified pattern, verbatim)
  const int krr = tid >> 3;
  const int kc8 = (tid & 7) * 8;
  const int vkr = lane;
  const int vd0 = wid * 8;

  v4u kr0, kr1, vr0, vr1;
  auto kv_load = [&](int kt) {
    const int key0 = kt * 64;
    kr0 = *(const v4u_ma*)(Kg + bbase + (size_t)(key0 + krr) * D_ + hoff + kc8);
    kr1 = *(const v4u_ma*)(Kg + bbase + (size_t)(key0 + 32 + krr) * D_ + hoff + kc8);
    vr0 = *(const v4u_ma*)(Vg + bbase + (size_t)(key0 + vkr) * D_ + hoff + vd0);
    vr1 = *(const v4u_ma*)(Vg + bbase + (size_t)(key0 + vkr) * D_ + hoff + vd0 + 32);
  };
  auto kv_write = [&]() {
    const int ksw = (krr & 7) << 4;
    *(v4u_ma*)((char*)Kl + krr * 128 + ((kc8 * 2) ^ ksw)) = kr0;
    *(v4u_ma*)((char*)Kl + (32 + krr) * 128 + ((kc8 * 2) ^ ksw)) = kr1;
    union {
      v4u v;
      u16 e[8];
    } uu;
    uu.v = vr0;
#pragma unroll
    for (int j = 0; j < 8; ++j) {
      const int d = vd0 + j;
      *(u16*)((char*)VTl + d * 128 + ((vkr * 2) ^ ((d & 7) << 4))) = uu.e[j];
    }
    uu.v = vr1;
#pragma unroll
    for (int j = 0; j < 8; ++j) {
      const int d = vd0 + 32 + j;
      *(u16*)((char*)VTl + d * 128 + ((vkr * 2) ^ ((d & 7) << 4))) = uu.e[j];
    }
  };

  kv_load(0);
  kv_write();

  const int swk = (l31 & 7) << 4;  // row&7 identical for l31 and 32+l31

  for (int kt = 0; kt < S_ / 64; ++kt) {
    __syncthreads();  // staged tile kt visible
    if (kt < S_ / 64 - 1) kv_load(kt + 1);  // T14 early issue

    // QK^T: sT[kh] = S[kh*32 + keyrow][q]; accumulate over 4 d-chunks (K=16)
    f32x16 sT0, sT1;
#pragma unroll
    for (int i = 0; i < 16; ++i) {
      sT0[i] = 0.f;
      sT1[i] = 0.f;
    }
    __builtin_amdgcn_s_setprio(1);
#pragma unroll
    for (int dblk = 0; dblk < 4; ++dblk) {
      const int cb = (dblk * 32 + hi * 16);
      bf16x8 a0 = *(const bf16x8_ma*)((const char*)Kl + l31 * 128 + (cb ^ swk));
      bf16x8 a1 =
          *(const bf16x8_ma*)((const char*)Kl + (32 + l31) * 128 + (cb ^ swk));
      sT0 = __builtin_amdgcn_mfma_f32_32x32x16_bf16(a0, bq[dblk], sT0, 0, 0, 0);
      sT1 = __builtin_amdgcn_mfma_f32_32x32x16_bf16(a1, bq[dblk], sT1, 0, 0, 0);
    }
    __builtin_amdgcn_s_setprio(0);

    // online softmax; lane owns q=q0w+l31, holds 32 of 64 key-scores
    float pmax = sT0[0];
#pragma unroll
    for (int i = 1; i < 16; ++i) pmax = fmaxf(pmax, sT0[i]);
#pragma unroll
    for (int i = 0; i < 16; ++i) pmax = fmaxf(pmax, sT1[i]);
    pmax = fmaxf(pmax, __shfl_xor(pmax, 32));
    // T13 defer-max: skip rescale while tile max stays within 8 of running max
    if (!__all(pmax - mrun <= 8.f)) {
      const float mnew = fmaxf(mrun, pmax);
      const float al = __expf(mrun - mnew);
      mrun = mnew;
      lrun *= al;
      o0 *= al;
      o1 *= al;
    }

    // p = exp(s - mrun); pack own dwords w[kh*8+g*2+u] = keys
    // (kh*32 + 8g + 4hi + 2u, +1)
    u32 w[16];
    float sum = 0.f;
#pragma unroll
    for (int kh = 0; kh < 2; ++kh)
#pragma unroll
      for (int g = 0; g < 4; ++g)
#pragma unroll
        for (int u = 0; u < 2; ++u) {
          const int r = g * 4 + 2 * u;
          const float pe =
              __expf((kh ? sT1[r] : sT0[r]) - mrun);
          const float po =
              __expf((kh ? sT1[r + 1] : sT0[r + 1]) - mrun);
          sum += pe + po;
          w[kh * 8 + g * 2 + u] = pkf(pe, po);
        }
    sum += __shfl_xor(sum, 32);
    lrun += sum;

    // P B-frags via pair exchange (lane <-> lane^32):
    // frag km = keys km*16 + hi*8 + {0..7}
    bf16x8 pf[4];
#pragma unroll
    for (int km = 0; km < 4; ++km) {
      const int a = 4 * km;
      const u32 s0 = hi ? w[a] : w[a + 2];
      const u32 s1 = hi ? w[a + 1] : w[a + 3];
      const u32 r0 = (u32)__shfl_xor((int)s0, 32);
      const u32 r1 = (u32)__shfl_xor((int)s1, 32);
      union {
        u32 d[4];
        bf16x8 v;
      } uu;
      uu.d[0] = hi ? r0 : w[a];
      uu.d[1] = hi ? r1 : w[a + 1];
      uu.d[2] = hi ? w[a + 2] : r0;
      uu.d[3] = hi ? w[a + 3] : r1;
      pf[km] = uu.v;
    }

    // PV: O^T += V^T P^T ; A-frag = V[key=km*16+hi*8+e][d=row] from VTl
    __builtin_amdgcn_s_setprio(1);
#pragma unroll
    for (int km = 0; km < 4; ++km) {
      const int cb = (km * 32 + hi * 16);
      bf16x8 v0 = *(const bf16x8_ma*)((const char*)VTl + l31 * 128 + (cb ^ swk));
      bf16x8 v1 =
          *(const bf16x8_ma*)((const char*)VTl + (32 + l31) * 128 + (cb ^ swk));
      o0 = __builtin_amdgcn_mfma_f32_32x32x16_bf16(v0, pf[km], o0, 0, 0, 0);
      o1 = __builtin_amdgcn_mfma_f32_32x32x16_bf16(v1, pf[km], o1, 0, 0, 0);
    }
    __builtin_amdgcn_s_setprio(0);

    __syncthreads();  // all waves done reading Kl/VTl
    if (kt < S_ / 64 - 1) kv_write();
  }

  // epilogue: lane holds O[q=q0w+l31][d=(r&3)+8*(r>>2)+4*hi (+32)]
  const float inv = 1.f / lrun;
  u16* orow = Og + bbase + (size_t)(q0w + l31) * D_ + hoff;
#pragma unroll
  for (int r = 0; r < 16; ++r) {
    const int d0 = (r & 3) + 8 * (r >> 2) + 4 * hi;
    orow[d0] = f2bf(o0[r] * inv);
    orow[d0 + 32] = f2bf(o1[r] * inv);
  }
}

// ---------------------------------------------------------------------------
// R5 golden slow path — fallback for small-ws worlds.
// ---------------------------------------------------------------------------
template <bool A_SCR, bool SCR_F32, bool OUT_FINAL>
__global__ __launch_bounds__(256) void proj_slow(
    const void* __restrict__ Ag, const u16* __restrict__ Wg,
    void* __restrict__ Cg) {
  const bool det = detect_f32(Wg);
  const bool a_f32 = A_SCR ? SCR_F32 : det;
  const int m = blockIdx.x;
  const int n = blockIdx.y * 256 + threadIdx.x;
  const size_t arow = (size_t)m * D_;
  const size_t wrow = (size_t)n * D_;
  float acc = 0.f;
  for (int k = 0; k < D_; ++k) {
    float a = a_f32 ? ((const f32_ma*)Ag)[arow + k]
                    : bf2f(((const u16_ma*)Ag)[arow + k]);
    float w = det ? ((const f32_ma*)Wg)[wrow + k]
                  : bf2f(((const u16_ma*)Wg)[wrow + k]);
    acc += a * w;
  }
  const size_t ci = (size_t)m * D_ + n;
  const bool c_f32 = OUT_FINAL ? det : SCR_F32;
  if (c_f32)
    ((f32_ma*)Cg)[ci] = acc;
  else
    ((u16_ma*)Cg)[ci] = f2bf(acc);
}

template <bool SCR_F32>
__global__ __launch_bounds__(256) void attn_slow(
    const void* __restrict__ Qg, const void* __restrict__ Kg,
    const void* __restrict__ Vg, void* __restrict__ Cg) {
  const int tid = threadIdx.x;
  const int qblk = blockIdx.x & 7;
  const int h = (blockIdx.x >> 3) & 15;
  const int b = blockIdx.x >> 7;
  const int q = qblk * 256 + tid;
  const size_t base = (size_t)b * S_ * D_;
  const int hoff = h * HD_;
  float qv[64];
  {
    const size_t qrow = base + (size_t)q * D_ + hoff;
    for (int d = 0; d < 64; ++d)
      qv[d] = SCR_F32 ? ((const f32_ma*)Qg)[qrow + d]
                      : bf2f(((const u16_ma*)Qg)[qrow + d]);
  }
  float o[64];
  for (int d = 0; d < 64; ++d) o[d] = 0.f;
  float m = -1e30f, l = 0.f;
  for (int key = 0; key < S_; ++key) {
    const size_t krow = base + (size_t)key * D_ + hoff;
    float s = 0.f;
    for (int d = 0; d < 64; ++d) {
      float kx = SCR_F32 ? ((const f32_ma*)Kg)[krow + d]
                         : bf2f(((const u16_ma*)Kg)[krow + d]);
      s += qv[d] * kx;
    }
    s *= 0.125f;
    float mn = fmaxf(m, s);
    float al = expf(m - mn);
    float pe = expf(s - mn);
    m = mn;
    l = l * al + pe;
    for (int d = 0; d < 64; ++d) {
      float vx = SCR_F32 ? ((const f32_ma*)Vg)[krow + d]
                         : bf2f(((const u16_ma*)Vg)[krow + d]);
      o[d] = o[d] * al + pe * vx;
    }
  }
  const float il = 1.f / l;
  const size_t crow = base + (size_t)q * D_ + hoff;
  for (int d = 0; d < 64; ++d) {
    if (SCR_F32)
      ((f32_ma*)Cg)[crow + d] = o[d] * il;
    else
      ((u16_ma*)Cg)[crow + d] = f2bf(o[d] * il);
  }
}

extern "C" void kernel_launch(void* const* d_in, const int* in_sizes, int n_in,
                              void* d_out, int out_size, void* d_ws,
                              size_t ws_size, hipStream_t stream) {
  const u16* Wdet = (const u16*)d_in[3];  // pristine Wq for dtype detect
  dim3 blk(256);

  if (ws_size >= (size_t)4 * NE_ * sizeof(float)) {
    u16* Qi = (u16*)d_ws;
    u16* Wc = Qi + (size_t)3 * NE_;
    u16* Qp = Wc + (size_t)4 * WN_;
    u16* Xp = Qp + (size_t)3 * NE_;

    convert_bf16<<<dim3(2048, 7), blk, 0, stream>>>(
        d_in[0], d_in[1], d_in[2], d_in[3], d_in[4], d_in[5], d_in[6], Qi, Wc,
        Wdet);
    proj_g<128, false><<<dim3(32, 8, 3), blk, 0, stream>>>(Qi, Wc, Qp, Wdet);
    attn3<<<dim3(512), blk, 0, stream>>>(Qp, Qp + NE_, Qp + (size_t)2 * NE_, Xp);
    proj_g<64, true><<<dim3(32, 16, 1), blk, 0, stream>>>(
        Xp, Wc + (size_t)3 * WN_, d_out, Wdet);
  } else {
    dim3 gproj(B_ * S_, D_ / 256);
    dim3 gattn(B_ * H_ * (S_ / 256));
    u16* Qp = (u16*)d_out;
    u16* Kp = (u16*)d_in[0];
    u16* Vp = (u16*)d_in[1];
    u16* Xp = (u16*)d_in[2];
    proj_slow<false, false, false><<<gproj, blk, 0, stream>>>(
        d_in[0], (const u16*)d_in[3], Qp);
    proj_slow<false, false, false><<<gproj, blk, 0, stream>>>(
        d_in[1], (const u16*)d_in[4], Kp);
    proj_slow<false, false, false><<<gproj, blk, 0, stream>>>(
        d_in[2], (const u16*)d_in[5], Vp);
    attn_slow<false><<<gattn, blk, 0, stream>>>(Qp, Kp, Vp, Xp);
    proj_slow<true, false, true><<<gproj, blk, 0, stream>>>(
        Xp, (const u16*)d_in[6], d_out);
  }
}